// Round 9
// baseline (316.327 us; speedup 1.0000x reference)
//
#include <hip/hip_runtime.h>

#define N_NODES 100000
#define N_EDGES 1600000
#define NCLS 40
#define NBUCK 196          // buckets of 512 nodes; bucket = id >> 9
#define CAPE 8960          // per-bucket edge capacity
#define CAPC 10752         // per-bucket CSR capacity incl. x8 padding
#define DUMMY N_NODES      // pad source id; dis[DUMMY] = 0, row DUMMY zeroed

typedef unsigned short u16;
typedef unsigned int u32;
typedef short bf16x8 __attribute__((ext_vector_type(8)));
typedef float f32x4 __attribute__((ext_vector_type(4)));

static inline size_t align256(size_t x) { return (x + 255) & ~(size_t)255; }

__device__ __forceinline__ float bf2f(u16 h) { return __uint_as_float(((u32)h) << 16); }
__device__ __forceinline__ u16 f2bf(float f) {
    u32 u = __float_as_uint(f);
    u += 0x7FFFu + ((u >> 16) & 1u);  // round-to-nearest-even
    return (u16)(u >> 16);
}
__device__ __forceinline__ float blo(u32 v) { return __uint_as_float(v << 16); }
__device__ __forceinline__ float bhi(u32 v) { return __uint_as_float(v & 0xFFFF0000u); }
__device__ __forceinline__ u32 pk2(u16 a, u16 b) { return (u32)a | ((u32)b << 16); }

// ---------- pass 1: LDS-histogram partition by bucket + fused x->bf16 ----------
#define PS_BLOCKS 391
#define CONV_BLOCKS 6250

__global__ __launch_bounds__(256) void pscatter_conv(const int* __restrict__ src,
                                                     const int* __restrict__ dst,
                                                     int* __restrict__ gFillD,
                                                     int* __restrict__ gFillS,
                                                     int2* __restrict__ partD,
                                                     int* __restrict__ partS,
                                                     const float* __restrict__ x,
                                                     u16* __restrict__ xb) {
    if (blockIdx.x >= PS_BLOCKS) {
        int i = (blockIdx.x - PS_BLOCKS) * 256 + threadIdx.x;  // 4 floats/thread
        float4 v = *(const float4*)(x + (size_t)i * 4);
        ushort4 o;
        o.x = f2bf(v.x); o.y = f2bf(v.y); o.z = f2bf(v.z); o.w = f2bf(v.w);
        *(ushort4*)(xb + (size_t)i * 4) = o;
        return;
    }
    __shared__ int histD[NBUCK], histS[NBUCK], chunkD[NBUCK], chunkS[NBUCK];
    int tid = threadIdx.x;
    int base = blockIdx.x * 4096;

    int4 sv[4], dv[4];
#pragma unroll
    for (int j = 0; j < 4; ++j) {
        int idx = base + j * 1024 + tid * 4;
        if (idx < N_EDGES) {
            sv[j] = *(const int4*)(src + idx);
            dv[j] = *(const int4*)(dst + idx);
        } else {
            sv[j] = make_int4(0, 0, 0, 0);
            dv[j] = make_int4(0, 0, 0, 0);
        }
    }

    for (int i = tid; i < NBUCK; i += 256) { histD[i] = 0; histS[i] = 0; }
    __syncthreads();
#pragma unroll
    for (int j = 0; j < 4; ++j)
#pragma unroll
        for (int k = 0; k < 4; ++k) {
            int s = ((const int*)&sv[j])[k], d = ((const int*)&dv[j])[k];
            if (s != d) {
                atomicAdd(&histD[d >> 9], 1);
                atomicAdd(&histS[s >> 9], 1);
            }
        }
    __syncthreads();
    for (int B = tid; B < NBUCK; B += 256) {
        int cD = histD[B];
        chunkD[B] = cD ? atomicAdd(&gFillD[B], cD) : 0;
        int cS = histS[B];
        chunkS[B] = cS ? atomicAdd(&gFillS[B], cS) : 0;
    }
    __syncthreads();
    for (int i = tid; i < NBUCK; i += 256) { histD[i] = 0; histS[i] = 0; }
    __syncthreads();
#pragma unroll
    for (int j = 0; j < 4; ++j)
#pragma unroll
        for (int k = 0; k < 4; ++k) {
            int s = ((const int*)&sv[j])[k], d = ((const int*)&dv[j])[k];
            if (s != d) {
                int bD = d >> 9;
                int r = atomicAdd(&histD[bD], 1);
                int o = chunkD[bD] + r;
                if (o < CAPE) partD[bD * CAPE + o] = make_int2(d, s);
                int bS = s >> 9;
                int r2 = atomicAdd(&histS[bS], 1);
                int o2 = chunkS[bS] + r2;
                if (o2 < CAPE) partS[bS * CAPE + o2] = s;
            }
        }
}

// ---------- pass 2: per-bucket CSR build (blocks [0,196)) / deg->dis (blocks [196,392)) ----------
__global__ __launch_bounds__(256) void build(const int2* __restrict__ partD,
                                             const int* __restrict__ partS,
                                             const int* __restrict__ gFillD,
                                             const int* __restrict__ gFillS,
                                             int* __restrict__ csr,
                                             int2* __restrict__ meta,
                                             float* __restrict__ dis) {
    __shared__ int cnt[512], loc[512], rnk[512];
    int tid = threadIdx.x;

    if (blockIdx.x >= NBUCK) {
        int B = blockIdx.x - NBUCK;
        for (int i = tid; i < 512; i += 256) cnt[i] = 0;
        __syncthreads();
        int nS = min(gFillS[B], CAPE);
        for (int i = tid; i < nS; i += 256) atomicAdd(&cnt[partS[B * CAPE + i] & 511], 1);
        __syncthreads();
        for (int n = tid; n < 512; n += 256) {
            int node = B * 512 + n;
            if (node < N_NODES) {
                int dg = cnt[n];
                dis[node] = dg > 0 ? 1.0f / sqrtf((float)dg) : 0.0f;
            }
        }
        return;
    }

    int B = blockIdx.x;
    for (int i = tid; i < 512; i += 256) { cnt[i] = 0; rnk[i] = 0; }
    __syncthreads();
    int nD = min(gFillD[B], CAPE);
    for (int i = tid; i < nD; i += 256) atomicAdd(&cnt[partD[B * CAPE + i].x & 511], 1);
    __syncthreads();
    if (tid < 64) {
        int bb = tid * 8, c8[8], mysum = 0;
#pragma unroll
        for (int j = 0; j < 8; ++j) { c8[j] = (cnt[bb + j] + 7) & ~7; mysum += c8[j]; }
        int incl = mysum;
#pragma unroll
        for (int off = 1; off < 64; off <<= 1) {
            int v = __shfl_up(incl, off);
            if (tid >= off) incl += v;
        }
        int run = incl - mysum;
#pragma unroll
        for (int j = 0; j < 8; ++j) { loc[bb + j] = run; run += c8[j]; }
    }
    __syncthreads();
    for (int n = tid; n < 512; n += 256) {
        int node = B * 512 + n;
        if (node < N_NODES) {
            meta[node] = make_int2(B * CAPC + loc[n], cnt[n]);
            int c = cnt[n], c8 = (c + 7) & ~7;   // pad list to x8 with DUMMY (w=0)
            for (int e = c; e < c8; ++e) csr[B * CAPC + loc[n] + e] = DUMMY;
        }
    }
    for (int i = tid; i < nD; i += 256) {
        int2 p = partD[B * CAPE + i];
        int ln = p.x & 511;
        int r = atomicAdd(&rnk[ln], 1);
        int pos = loc[ln] + r;
        if (pos < CAPC) csr[B * CAPC + pos] = p.y;
    }
}

// ---------- SPMM gather8 (one wave/node; 8 edges per row-load instruction) ----------
// lane = (g,p): group g=lane>>3 owns edge e+g; slot p=lane&7 owns feature chunk [8p,8p+8).
// Per 8 edges: 1 csr dword + 1 dis dword + 1 row dwordx4 (full 128B row per group).
// acc over edges -> shfl_xor(8/16/32) tree; groups 0/1 write hi/lo bf16 planes.
__global__ __launch_bounds__(256) void spmm(const u16* __restrict__ in,     // (N+1)x64 bf16
                                            const float* __restrict__ dis,  // N+1, dis[N]=0
                                            const int2* __restrict__ meta,
                                            const int* __restrict__ csr,
                                            const float* __restrict__ subf,
                                            const u16* __restrict__ subh,
                                            const u16* __restrict__ subl,
                                            u16* __restrict__ outhi,
                                            u16* __restrict__ outlo) {
    int node = (blockIdx.x * 256 + threadIdx.x) >> 6;
    int lane = threadIdx.x & 63;
    if (node >= N_NODES) return;
    int2 mt = meta[node];
    int c8 = (mt.y + 7) & ~7;          // lists DUMMY-padded to x8
    const int* lst = csr + mt.x;
    const uint4* in4 = (const uint4*)in;
    const int g = lane >> 3;
    const int p = lane & 7;

    float a0 = 0.f, a1 = 0.f, a2 = 0.f, a3 = 0.f, a4 = 0.f, a5 = 0.f, a6 = 0.f, a7 = 0.f;
    for (int e = 0; e < c8; e += 8) {
        int s = lst[e + g];
        float w = dis[s];
        uint4 v = in4[((u32)s << 3) + p];
        a0 = fmaf(w, blo(v.x), a0);
        a1 = fmaf(w, bhi(v.x), a1);
        a2 = fmaf(w, blo(v.y), a2);
        a3 = fmaf(w, bhi(v.y), a3);
        a4 = fmaf(w, blo(v.z), a4);
        a5 = fmaf(w, bhi(v.z), a5);
        a6 = fmaf(w, blo(v.w), a6);
        a7 = fmaf(w, bhi(v.w), a7);
    }
    // sum across the 8 groups (every lane ends with the full sum)
#pragma unroll
    for (int m = 8; m <= 32; m <<= 1) {
        a0 += __shfl_xor(a0, m);
        a1 += __shfl_xor(a1, m);
        a2 += __shfl_xor(a2, m);
        a3 += __shfl_xor(a3, m);
        a4 += __shfl_xor(a4, m);
        a5 += __shfl_xor(a5, m);
        a6 += __shfl_xor(a6, m);
        a7 += __shfl_xor(a7, m);
    }
    float vd = -dis[node];
    float f[8] = {vd * a0, vd * a1, vd * a2, vd * a3, vd * a4, vd * a5, vd * a6, vd * a7};
    if (subf) {
        const float4* s4 = (const float4*)(subf + ((size_t)node << 6) + (p << 3));
        float4 sa = s4[0], sb = s4[1];
        f[0] = 2.0f * f[0] - sa.x; f[1] = 2.0f * f[1] - sa.y;
        f[2] = 2.0f * f[2] - sa.z; f[3] = 2.0f * f[3] - sa.w;
        f[4] = 2.0f * f[4] - sb.x; f[5] = 2.0f * f[5] - sb.y;
        f[6] = 2.0f * f[6] - sb.z; f[7] = 2.0f * f[7] - sb.w;
    } else if (subh) {
        uint4 sh = *((const uint4*)(subh + ((size_t)node << 6)) + p);
        uint4 sl = *((const uint4*)(subl + ((size_t)node << 6)) + p);
        const u32* shw = (const u32*)&sh;
        const u32* slw = (const u32*)&sl;
#pragma unroll
        for (int k = 0; k < 4; ++k) {
            f[2 * k] = 2.0f * f[2 * k] - (blo(shw[k]) + blo(slw[k]));
            f[2 * k + 1] = 2.0f * f[2 * k + 1] - (bhi(shw[k]) + bhi(slw[k]));
        }
    }
    if (g == 0) {
        uint4 H;
        H.x = pk2(f2bf(f[0]), f2bf(f[1]));
        H.y = pk2(f2bf(f[2]), f2bf(f[3]));
        H.z = pk2(f2bf(f[4]), f2bf(f[5]));
        H.w = pk2(f2bf(f[6]), f2bf(f[7]));
        *((uint4*)(outhi + ((size_t)node << 6)) + p) = H;
    } else if (g == 1) {
        uint4 L;
        u16 l0 = f2bf(f[0] - bf2f(f2bf(f[0])));
        u16 l1 = f2bf(f[1] - bf2f(f2bf(f[1])));
        u16 l2 = f2bf(f[2] - bf2f(f2bf(f[2])));
        u16 l3 = f2bf(f[3] - bf2f(f2bf(f[3])));
        u16 l4 = f2bf(f[4] - bf2f(f2bf(f[4])));
        u16 l5 = f2bf(f[5] - bf2f(f2bf(f[5])));
        u16 l6 = f2bf(f[6] - bf2f(f2bf(f[6])));
        u16 l7 = f2bf(f[7] - bf2f(f2bf(f[7])));
        L.x = pk2(l0, l1); L.y = pk2(l2, l3); L.z = pk2(l4, l5); L.w = pk2(l6, l7);
        *((uint4*)(outlo + ((size_t)node << 6)) + p) = L;
    }
}

// ---------- dense via MFMA with split-bf16 (fp32-equivalent accuracy) ----------
#define DGRID 1250
#define DNT 5              // 1250 * 5 * 16 = 100000 rows exactly
#define LSTR 200           // u16 per LDS row (192 data + 8 pad)

__global__ __launch_bounds__(256) void dense1_mf(const float* __restrict__ x,
                                                 const u16* __restrict__ a1h,
                                                 const u16* __restrict__ a1l,
                                                 const u16* __restrict__ a2h,
                                                 const u16* __restrict__ a2l,
                                                 const float* __restrict__ W,
                                                 const float* __restrict__ bias,
                                                 u16* __restrict__ ohi,
                                                 u16* __restrict__ olo) {
    __shared__ u16 Ah[16 * LSTR], Al[16 * LSTR];
    const int tid = threadIdx.x, wid = tid >> 6, lane = tid & 63;
    const int lrow = lane & 15, lk8 = (lane >> 4) * 8;
    const int col = wid * 16 + lrow;

    bf16x8 wh[6], wl[6];
#pragma unroll
    for (int c = 0; c < 6; ++c) {
        bf16x8 h, l;
#pragma unroll
        for (int i = 0; i < 8; ++i) {
            float wv = W[(c * 32 + lk8 + i) * 64 + col];
            u16 hb_ = f2bf(wv);
            h[i] = (short)hb_;
            l[i] = (short)f2bf(wv - bf2f(hb_));
        }
        wh[c] = h; wl[c] = l;
    }
    float bv = bias[col];
    const int srow = tid >> 4, sc4 = (tid & 15) * 4;

    for (int t = 0; t < DNT; ++t) {
        int r0 = (blockIdx.x * DNT + t) * 16;
        size_t rb = ((size_t)(r0 + srow) << 6) + sc4;
        {
            float4 v = *(const float4*)&x[rb];
            const float* vp = (const float*)&v;
            ushort4 hv, lv;
#pragma unroll
            for (int i = 0; i < 4; ++i) {
                u16 hb_ = f2bf(vp[i]);
                ((u16*)&hv)[i] = hb_;
                ((u16*)&lv)[i] = f2bf(vp[i] - bf2f(hb_));
            }
            *(ushort4*)&Ah[srow * LSTR + sc4] = hv;
            *(ushort4*)&Al[srow * LSTR + sc4] = lv;
        }
        *(ushort4*)&Ah[srow * LSTR + 64 + sc4] = *(const ushort4*)&a1h[rb];
        *(ushort4*)&Al[srow * LSTR + 64 + sc4] = *(const ushort4*)&a1l[rb];
        *(ushort4*)&Ah[srow * LSTR + 128 + sc4] = *(const ushort4*)&a2h[rb];
        *(ushort4*)&Al[srow * LSTR + 128 + sc4] = *(const ushort4*)&a2l[rb];
        __syncthreads();

        f32x4 acc = {bv, bv, bv, bv};
#pragma unroll
        for (int c = 0; c < 6; ++c) {
            bf16x8 ah = *(const bf16x8*)&Ah[lrow * LSTR + c * 32 + lk8];
            bf16x8 al = *(const bf16x8*)&Al[lrow * LSTR + c * 32 + lk8];
            acc = __builtin_amdgcn_mfma_f32_16x16x32_bf16(ah, wh[c], acc, 0, 0, 0);
            acc = __builtin_amdgcn_mfma_f32_16x16x32_bf16(al, wh[c], acc, 0, 0, 0);
            acc = __builtin_amdgcn_mfma_f32_16x16x32_bf16(ah, wl[c], acc, 0, 0, 0);
        }
        __syncthreads();

#pragma unroll
        for (int j = 0; j < 4; ++j) {
            int row = r0 + (lane >> 4) * 4 + j;
            float v = fmaxf(acc[j], 0.0f);
            u16 hb_ = f2bf(v);
            ohi[((size_t)row << 6) + col] = hb_;
            olo[((size_t)row << 6) + col] = f2bf(v - bf2f(hb_));
        }
    }
}

__global__ __launch_bounds__(256) void dense2_mf(const u16* __restrict__ a0h,
                                                 const u16* __restrict__ a0l,
                                                 const u16* __restrict__ a1h,
                                                 const u16* __restrict__ a1l,
                                                 const u16* __restrict__ a2h,
                                                 const u16* __restrict__ a2l,
                                                 const float* __restrict__ W,
                                                 const float* __restrict__ bias,
                                                 float* __restrict__ out) {
    __shared__ u16 Ah[16 * LSTR], Al[16 * LSTR];
    __shared__ float Ls[16][48];
    const int tid = threadIdx.x, wid = tid >> 6, lane = tid & 63;
    const int lrow = lane & 15, lk8 = (lane >> 4) * 8;
    const int col = wid * 16 + lrow;
    const bool act = (wid < 3);
    const bool cok = act && (col < NCLS);

    bf16x8 wh[6], wl[6];
#pragma unroll
    for (int c = 0; c < 6; ++c) {
        bf16x8 h = 0, l = 0;
        if (cok) {
#pragma unroll
            for (int i = 0; i < 8; ++i) {
                float wv = W[(c * 32 + lk8 + i) * NCLS + col];
                u16 hb_ = f2bf(wv);
                h[i] = (short)hb_;
                l[i] = (short)f2bf(wv - bf2f(hb_));
            }
        }
        wh[c] = h; wl[c] = l;
    }
    float bv = cok ? bias[col] : 0.0f;
    const int srow = tid >> 4, sc4 = (tid & 15) * 4;

    for (int t = 0; t < DNT; ++t) {
        int r0 = (blockIdx.x * DNT + t) * 16;
        size_t rb = ((size_t)(r0 + srow) << 6) + sc4;
        *(ushort4*)&Ah[srow * LSTR + sc4] = *(const ushort4*)&a0h[rb];
        *(ushort4*)&Al[srow * LSTR + sc4] = *(const ushort4*)&a0l[rb];
        *(ushort4*)&Ah[srow * LSTR + 64 + sc4] = *(const ushort4*)&a1h[rb];
        *(ushort4*)&Al[srow * LSTR + 64 + sc4] = *(const ushort4*)&a1l[rb];
        *(ushort4*)&Ah[srow * LSTR + 128 + sc4] = *(const ushort4*)&a2h[rb];
        *(ushort4*)&Al[srow * LSTR + 128 + sc4] = *(const ushort4*)&a2l[rb];
        __syncthreads();

        if (act) {
            f32x4 acc = {bv, bv, bv, bv};
#pragma unroll
            for (int c = 0; c < 6; ++c) {
                bf16x8 ah = *(const bf16x8*)&Ah[lrow * LSTR + c * 32 + lk8];
                bf16x8 al = *(const bf16x8*)&Al[lrow * LSTR + c * 32 + lk8];
                acc = __builtin_amdgcn_mfma_f32_16x16x32_bf16(ah, wh[c], acc, 0, 0, 0);
                acc = __builtin_amdgcn_mfma_f32_16x16x32_bf16(al, wh[c], acc, 0, 0, 0);
                acc = __builtin_amdgcn_mfma_f32_16x16x32_bf16(ah, wl[c], acc, 0, 0, 0);
            }
#pragma unroll
            for (int j = 0; j < 4; ++j) Ls[(lane >> 4) * 4 + j][col] = acc[j];
        }
        __syncthreads();

        {   // softmax: 16 rows, one 16-lane group per row (4 rows per wave)
            int row = wid * 4 + (lane >> 4);
            int cg = lane & 15;
            float v0 = Ls[row][cg];
            float v1 = Ls[row][cg + 16];
            float v2 = (cg < 8) ? Ls[row][cg + 32] : -1e30f;
            float m = fmaxf(fmaxf(v0, v1), v2);
#pragma unroll
            for (int o = 8; o; o >>= 1) m = fmaxf(m, __shfl_xor(m, o));
            float e0 = expf(v0 - m), e1 = expf(v1 - m);
            float e2 = (cg < 8) ? expf(v2 - m) : 0.0f;
            float s = e0 + e1 + e2;
#pragma unroll
            for (int o = 8; o; o >>= 1) s += __shfl_xor(s, o);
            float inv = 1.0f / s;
            size_t ob = (size_t)(r0 + row) * NCLS;
            out[ob + cg] = e0 * inv;
            out[ob + cg + 16] = e1 * inv;
            if (cg < 8) out[ob + cg + 32] = e2 * inv;
        }
    }
}

// ---------------- host ----------------

extern "C" void kernel_launch(void* const* d_in, const int* in_sizes, int n_in,
                              void* d_out, int out_size, void* d_ws, size_t ws_size,
                              hipStream_t stream) {
    const float* x = (const float*)d_in[0];
    const int* edge_index = (const int*)d_in[1];
    const float* W1 = (const float*)d_in[2];
    const float* b1 = (const float*)d_in[3];
    const float* W2 = (const float*)d_in[4];
    const float* b2 = (const float*)d_in[5];
    float* out = (float*)d_out;

    const int* src = edge_index;
    const int* dst = edge_index + N_EDGES;

    char* ws = (char*)d_ws;
    size_t off = 0;
    auto carve = [&](size_t bytes) -> void* {
        void* p = ws + off;
        off = align256(off + bytes);
        return p;
    };
    int* gFillD = (int*)carve((size_t)NBUCK * 4);
    int* gFillS = (int*)carve((size_t)NBUCK * 4);
    size_t zero_bytes = off;
    int2* partD = (int2*)carve((size_t)NBUCK * CAPE * 8);   // 14.0 MB
    int* partS = (int*)carve((size_t)NBUCK * CAPE * 4);     // 7.0 MB
    int* csr = (int*)carve((size_t)NBUCK * CAPC * 4 + 1024);// 8.4 MB (+slack)
    int2* meta = (int2*)carve((size_t)N_NODES * 8);         // 0.8 MB
    float* dis = (float*)carve((size_t)(N_NODES + 1) * 4);  // 0.4 MB (+DUMMY)
    const size_t FB = (size_t)(N_NODES + 1) * 64 * 2;       // 12.8 MB per bf16 plane (+DUMMY row)
    u16* xb  = (u16*)carve(FB);
    u16* t1h = (u16*)carve(FB);   // Tx1 / Th1 hi
    u16* t1l = (u16*)carve(FB);   // Tx1 / Th1 lo
    u16* t2h = (u16*)carve(FB);   // Tx2 / Th2 hi
    u16* t2l = (u16*)carve(FB);   // Tx2 / Th2 lo
    u16* hh  = (u16*)carve(FB);   // h hi (gather input for layer 2)
    u16* hl  = (u16*)carve(FB);   // h lo
    // total ~120 MB

    const int WV = (N_NODES * 64) / 256;    // 25000 (one wave per node)

    hipMemsetAsync(d_ws, 0, zero_bytes, stream);
    hipMemsetAsync(dis + N_NODES, 0, 4, stream);               // dis[DUMMY] = 0
    hipMemsetAsync(xb + (size_t)N_NODES * 64, 0, 128, stream); // zero DUMMY rows of
    hipMemsetAsync(t1h + (size_t)N_NODES * 64, 0, 128, stream);//   all gather inputs
    hipMemsetAsync(hh + (size_t)N_NODES * 64, 0, 128, stream);

    pscatter_conv<<<PS_BLOCKS + CONV_BLOCKS, 256, 0, stream>>>(src, dst, gFillD, gFillS,
                                                               partD, partS, x, xb);
    build<<<2 * NBUCK, 256, 0, stream>>>(partD, partS, gFillD, gFillS, csr, meta, dis);

    // layer 1
    spmm<<<WV, 256, 0, stream>>>(xb, dis, meta, csr, nullptr, nullptr, nullptr, t1h, t1l);
    spmm<<<WV, 256, 0, stream>>>(t1h, dis, meta, csr, x, nullptr, nullptr, t2h, t2l);
    dense1_mf<<<DGRID, 256, 0, stream>>>(x, t1h, t1l, t2h, t2l, W1, b1, hh, hl);

    // layer 2 (t1/t2 planes reused)
    spmm<<<WV, 256, 0, stream>>>(hh, dis, meta, csr, nullptr, nullptr, nullptr, t1h, t1l);
    spmm<<<WV, 256, 0, stream>>>(t1h, dis, meta, csr, nullptr, hh, hl, t2h, t2l);
    dense2_mf<<<DGRID, 256, 0, stream>>>(hh, hl, t1h, t1l, t2h, t2l, W2, b2, out);
}

// Round 10
// 270.670 us; speedup vs baseline: 1.1687x; 1.1687x over previous
//
#include <hip/hip_runtime.h>

#define N_NODES 100000
#define N_EDGES 1600000
#define NCLS 40
#define NBUCK 196          // buckets of 512 nodes; bucket = id >> 9
#define CAPE 8960          // per-bucket edge capacity
#define CAPC 10752         // per-bucket CSR capacity incl. x8 padding
#define DUMMY N_NODES      // pad source id; dis[DUMMY] = 0, row DUMMY zeroed

typedef unsigned short u16;
typedef unsigned int u32;
typedef short bf16x8 __attribute__((ext_vector_type(8)));
typedef float f32x4 __attribute__((ext_vector_type(4)));

static inline size_t align256(size_t x) { return (x + 255) & ~(size_t)255; }

__device__ __forceinline__ float bf2f(u16 h) { return __uint_as_float(((u32)h) << 16); }
__device__ __forceinline__ u16 f2bf(float f) {
    u32 u = __float_as_uint(f);
    u += 0x7FFFu + ((u >> 16) & 1u);  // round-to-nearest-even
    return (u16)(u >> 16);
}
__device__ __forceinline__ u32 pk2(u16 a, u16 b) { return (u32)a | ((u32)b << 16); }

// ---------- pass 1: LDS-histogram partition by bucket + fused x->bf16 ----------
#define PS_BLOCKS 391
#define CONV_BLOCKS 6250

__global__ __launch_bounds__(256) void pscatter_conv(const int* __restrict__ src,
                                                     const int* __restrict__ dst,
                                                     int* __restrict__ gFillD,
                                                     int* __restrict__ gFillS,
                                                     int2* __restrict__ partD,
                                                     int* __restrict__ partS,
                                                     const float* __restrict__ x,
                                                     u16* __restrict__ xb) {
    if (blockIdx.x >= PS_BLOCKS) {
        int i = (blockIdx.x - PS_BLOCKS) * 256 + threadIdx.x;  // 4 floats/thread
        float4 v = *(const float4*)(x + (size_t)i * 4);
        ushort4 o;
        o.x = f2bf(v.x); o.y = f2bf(v.y); o.z = f2bf(v.z); o.w = f2bf(v.w);
        *(ushort4*)(xb + (size_t)i * 4) = o;
        return;
    }
    __shared__ int histD[NBUCK], histS[NBUCK], chunkD[NBUCK], chunkS[NBUCK];
    int tid = threadIdx.x;
    int base = blockIdx.x * 4096;

    int4 sv[4], dv[4];
#pragma unroll
    for (int j = 0; j < 4; ++j) {
        int idx = base + j * 1024 + tid * 4;
        if (idx < N_EDGES) {
            sv[j] = *(const int4*)(src + idx);
            dv[j] = *(const int4*)(dst + idx);
        } else {
            sv[j] = make_int4(0, 0, 0, 0);
            dv[j] = make_int4(0, 0, 0, 0);
        }
    }

    for (int i = tid; i < NBUCK; i += 256) { histD[i] = 0; histS[i] = 0; }
    __syncthreads();
#pragma unroll
    for (int j = 0; j < 4; ++j)
#pragma unroll
        for (int k = 0; k < 4; ++k) {
            int s = ((const int*)&sv[j])[k], d = ((const int*)&dv[j])[k];
            if (s != d) {
                atomicAdd(&histD[d >> 9], 1);
                atomicAdd(&histS[s >> 9], 1);
            }
        }
    __syncthreads();
    for (int B = tid; B < NBUCK; B += 256) {
        int cD = histD[B];
        chunkD[B] = cD ? atomicAdd(&gFillD[B], cD) : 0;
        int cS = histS[B];
        chunkS[B] = cS ? atomicAdd(&gFillS[B], cS) : 0;
    }
    __syncthreads();
    for (int i = tid; i < NBUCK; i += 256) { histD[i] = 0; histS[i] = 0; }
    __syncthreads();
#pragma unroll
    for (int j = 0; j < 4; ++j)
#pragma unroll
        for (int k = 0; k < 4; ++k) {
            int s = ((const int*)&sv[j])[k], d = ((const int*)&dv[j])[k];
            if (s != d) {
                int bD = d >> 9;
                int r = atomicAdd(&histD[bD], 1);
                int o = chunkD[bD] + r;
                if (o < CAPE) partD[bD * CAPE + o] = make_int2(d, s);
                int bS = s >> 9;
                int r2 = atomicAdd(&histS[bS], 1);
                int o2 = chunkS[bS] + r2;
                if (o2 < CAPE) partS[bS * CAPE + o2] = s;
            }
        }
}

// ---------- pass 2: per-bucket CSR build (blocks [0,196)) / deg->dis (blocks [196,392)) ----------
__global__ __launch_bounds__(256) void build(const int2* __restrict__ partD,
                                             const int* __restrict__ partS,
                                             const int* __restrict__ gFillD,
                                             const int* __restrict__ gFillS,
                                             int* __restrict__ csr,
                                             int2* __restrict__ meta,
                                             float* __restrict__ dis) {
    __shared__ int cnt[512], loc[512], rnk[512];
    int tid = threadIdx.x;

    if (blockIdx.x >= NBUCK) {
        int B = blockIdx.x - NBUCK;
        for (int i = tid; i < 512; i += 256) cnt[i] = 0;
        __syncthreads();
        int nS = min(gFillS[B], CAPE);
        for (int i = tid; i < nS; i += 256) atomicAdd(&cnt[partS[B * CAPE + i] & 511], 1);
        __syncthreads();
        for (int n = tid; n < 512; n += 256) {
            int node = B * 512 + n;
            if (node < N_NODES) {
                int dg = cnt[n];
                dis[node] = dg > 0 ? 1.0f / sqrtf((float)dg) : 0.0f;
            }
        }
        return;
    }

    int B = blockIdx.x;
    for (int i = tid; i < 512; i += 256) { cnt[i] = 0; rnk[i] = 0; }
    __syncthreads();
    int nD = min(gFillD[B], CAPE);
    for (int i = tid; i < nD; i += 256) atomicAdd(&cnt[partD[B * CAPE + i].x & 511], 1);
    __syncthreads();
    if (tid < 64) {
        int bb = tid * 8, c8[8], mysum = 0;
#pragma unroll
        for (int j = 0; j < 8; ++j) { c8[j] = (cnt[bb + j] + 7) & ~7; mysum += c8[j]; }
        int incl = mysum;
#pragma unroll
        for (int off = 1; off < 64; off <<= 1) {
            int v = __shfl_up(incl, off);
            if (tid >= off) incl += v;
        }
        int run = incl - mysum;
#pragma unroll
        for (int j = 0; j < 8; ++j) { loc[bb + j] = run; run += c8[j]; }
    }
    __syncthreads();
    for (int n = tid; n < 512; n += 256) {
        int node = B * 512 + n;
        if (node < N_NODES) {
            meta[node] = make_int2(B * CAPC + loc[n], cnt[n]);
            int c = cnt[n], c8 = (c + 7) & ~7;   // pad list to x8 with DUMMY (w=0)
            for (int e = c; e < c8; ++e) csr[B * CAPC + loc[n] + e] = DUMMY;
        }
    }
    for (int i = tid; i < nD; i += 256) {
        int2 p = partD[B * CAPE + i];
        int ln = p.x & 511;
        int r = atomicAdd(&rnk[ln], 1);
        int pos = loc[ln] + r;
        if (pos < CAPC) csr[B * CAPC + pos] = p.y;
    }
}

// ---------- SPMM pure pair-gather (round-8 structure, 16-edge unroll) ----------
// lanes 0-31: even edges, lanes 32-63: odd edges; each lane covers 2 features (u32).
// v = -dis[node] * sum_e dis[s_e]*in[s_e,:]; half 0 writes hi plane, half 1 lo plane.
__global__ __launch_bounds__(256) void spmm(const u16* __restrict__ in,     // (N+1)x64 bf16
                                            const float* __restrict__ dis,  // N+1, dis[N]=0
                                            const int2* __restrict__ meta,
                                            const int* __restrict__ csr,
                                            u16* __restrict__ outhi,
                                            u16* __restrict__ outlo) {
    int node = (blockIdx.x * 256 + threadIdx.x) >> 6;
    int lane = threadIdx.x & 63;
    if (node >= N_NODES) return;
    int2 mt = meta[node];
    int c8 = (mt.y + 7) & ~7;          // lists DUMMY-padded to x8
    const int* lst = csr + mt.x;       // 32B-aligned
    const u32* in32 = (const u32*)in;
    const int hsel = lane >> 5;
    const int fl = lane & 31;
    float acc0 = 0.0f, acc1 = 0.0f;
    int e = 0;
    for (; e + 16 <= c8; e += 16) {     // 8 independent row-pair loads in flight
        int4 sa = *(const int4*)(lst + e);
        int4 sb = *(const int4*)(lst + e + 4);
        int4 sc = *(const int4*)(lst + e + 8);
        int4 sd = *(const int4*)(lst + e + 12);
        int s0 = hsel ? sa.y : sa.x;
        int s1 = hsel ? sa.w : sa.z;
        int s2 = hsel ? sb.y : sb.x;
        int s3 = hsel ? sb.w : sb.z;
        int s4 = hsel ? sc.y : sc.x;
        int s5 = hsel ? sc.w : sc.z;
        int s6 = hsel ? sd.y : sd.x;
        int s7 = hsel ? sd.w : sd.z;
        u32 v0 = in32[((u32)s0 << 5) + fl];
        u32 v1 = in32[((u32)s1 << 5) + fl];
        u32 v2 = in32[((u32)s2 << 5) + fl];
        u32 v3 = in32[((u32)s3 << 5) + fl];
        u32 v4 = in32[((u32)s4 << 5) + fl];
        u32 v5 = in32[((u32)s5 << 5) + fl];
        u32 v6 = in32[((u32)s6 << 5) + fl];
        u32 v7 = in32[((u32)s7 << 5) + fl];
        float w0 = dis[s0], w1 = dis[s1], w2 = dis[s2], w3 = dis[s3];
        float w4 = dis[s4], w5 = dis[s5], w6 = dis[s6], w7 = dis[s7];
        acc0 = fmaf(w0, __uint_as_float(v0 << 16), acc0);
        acc1 = fmaf(w0, __uint_as_float(v0 & 0xFFFF0000u), acc1);
        acc0 = fmaf(w1, __uint_as_float(v1 << 16), acc0);
        acc1 = fmaf(w1, __uint_as_float(v1 & 0xFFFF0000u), acc1);
        acc0 = fmaf(w2, __uint_as_float(v2 << 16), acc0);
        acc1 = fmaf(w2, __uint_as_float(v2 & 0xFFFF0000u), acc1);
        acc0 = fmaf(w3, __uint_as_float(v3 << 16), acc0);
        acc1 = fmaf(w3, __uint_as_float(v3 & 0xFFFF0000u), acc1);
        acc0 = fmaf(w4, __uint_as_float(v4 << 16), acc0);
        acc1 = fmaf(w4, __uint_as_float(v4 & 0xFFFF0000u), acc1);
        acc0 = fmaf(w5, __uint_as_float(v5 << 16), acc0);
        acc1 = fmaf(w5, __uint_as_float(v5 & 0xFFFF0000u), acc1);
        acc0 = fmaf(w6, __uint_as_float(v6 << 16), acc0);
        acc1 = fmaf(w6, __uint_as_float(v6 & 0xFFFF0000u), acc1);
        acc0 = fmaf(w7, __uint_as_float(v7 << 16), acc0);
        acc1 = fmaf(w7, __uint_as_float(v7 & 0xFFFF0000u), acc1);
    }
    if (e < c8) {                      // remainder: exactly 8 edges
        int4 sa = *(const int4*)(lst + e);
        int4 sb = *(const int4*)(lst + e + 4);
        int s0 = hsel ? sa.y : sa.x;
        int s1 = hsel ? sa.w : sa.z;
        int s2 = hsel ? sb.y : sb.x;
        int s3 = hsel ? sb.w : sb.z;
        u32 v0 = in32[((u32)s0 << 5) + fl];
        u32 v1 = in32[((u32)s1 << 5) + fl];
        u32 v2 = in32[((u32)s2 << 5) + fl];
        u32 v3 = in32[((u32)s3 << 5) + fl];
        float w0 = dis[s0], w1 = dis[s1], w2 = dis[s2], w3 = dis[s3];
        acc0 = fmaf(w0, __uint_as_float(v0 << 16), acc0);
        acc1 = fmaf(w0, __uint_as_float(v0 & 0xFFFF0000u), acc1);
        acc0 = fmaf(w1, __uint_as_float(v1 << 16), acc0);
        acc1 = fmaf(w1, __uint_as_float(v1 & 0xFFFF0000u), acc1);
        acc0 = fmaf(w2, __uint_as_float(v2 << 16), acc0);
        acc1 = fmaf(w2, __uint_as_float(v2 & 0xFFFF0000u), acc1);
        acc0 = fmaf(w3, __uint_as_float(v3 << 16), acc0);
        acc1 = fmaf(w3, __uint_as_float(v3 & 0xFFFF0000u), acc1);
    }
    acc0 += __shfl_xor(acc0, 32);
    acc1 += __shfl_xor(acc1, 32);
    float vd = -dis[node];
    float f0 = vd * acc0, f1 = vd * acc1;
    u32 o32 = ((u32)node << 5) + fl;
    u16 h0 = f2bf(f0), h1 = f2bf(f1);
    if (hsel == 0) {
        ((u32*)outhi)[o32] = pk2(h0, h1);
    } else {
        ((u32*)outlo)[o32] = pk2(f2bf(f0 - bf2f(h0)), f2bf(f1 - bf2f(h1)));
    }
}

// ---------- dense via MFMA, split-bf16, Chebyshev fold in the weights ----------
// out = A0@(W0 - W2) + A1@W1 + Ty@(2*W2)   where Ty = L.A1  (no Tx2 buffer needed)
#define DGRID 1250
#define DNT 5              // 1250 * 5 * 16 = 100000 rows exactly
#define LSTR 200           // u16 per LDS row (192 data + 8 pad)

__device__ __forceinline__ float foldW(const float* __restrict__ W, int kk, int col,
                                       int ncols) {
    float wv = W[kk * ncols + col];
    if (kk < 64) wv -= W[(kk + 128) * ncols + col];   // W0 - W2
    else if (kk >= 128) wv += wv;                     // 2 * W2
    return wv;
}

__global__ __launch_bounds__(256) void dense1_mf(const float* __restrict__ x,
                                                 const u16* __restrict__ a1h,
                                                 const u16* __restrict__ a1l,
                                                 const u16* __restrict__ tyh,
                                                 const u16* __restrict__ tyl,
                                                 const float* __restrict__ W,
                                                 const float* __restrict__ bias,
                                                 u16* __restrict__ ohi,
                                                 u16* __restrict__ olo) {
    __shared__ u16 Ah[16 * LSTR], Al[16 * LSTR];
    const int tid = threadIdx.x, wid = tid >> 6, lane = tid & 63;
    const int lrow = lane & 15, lk8 = (lane >> 4) * 8;
    const int col = wid * 16 + lrow;

    bf16x8 wh[6], wl[6];
#pragma unroll
    for (int c = 0; c < 6; ++c) {
        bf16x8 h, l;
#pragma unroll
        for (int i = 0; i < 8; ++i) {
            float wv = foldW(W, c * 32 + lk8 + i, col, 64);
            u16 hb_ = f2bf(wv);
            h[i] = (short)hb_;
            l[i] = (short)f2bf(wv - bf2f(hb_));
        }
        wh[c] = h; wl[c] = l;
    }
    float bv = bias[col];
    const int srow = tid >> 4, sc4 = (tid & 15) * 4;

    for (int t = 0; t < DNT; ++t) {
        int r0 = (blockIdx.x * DNT + t) * 16;
        size_t rb = ((size_t)(r0 + srow) << 6) + sc4;
        {
            float4 v = *(const float4*)&x[rb];
            const float* vp = (const float*)&v;
            ushort4 hv, lv;
#pragma unroll
            for (int i = 0; i < 4; ++i) {
                u16 hb_ = f2bf(vp[i]);
                ((u16*)&hv)[i] = hb_;
                ((u16*)&lv)[i] = f2bf(vp[i] - bf2f(hb_));
            }
            *(ushort4*)&Ah[srow * LSTR + sc4] = hv;
            *(ushort4*)&Al[srow * LSTR + sc4] = lv;
        }
        *(ushort4*)&Ah[srow * LSTR + 64 + sc4] = *(const ushort4*)&a1h[rb];
        *(ushort4*)&Al[srow * LSTR + 64 + sc4] = *(const ushort4*)&a1l[rb];
        *(ushort4*)&Ah[srow * LSTR + 128 + sc4] = *(const ushort4*)&tyh[rb];
        *(ushort4*)&Al[srow * LSTR + 128 + sc4] = *(const ushort4*)&tyl[rb];
        __syncthreads();

        f32x4 acc = {bv, bv, bv, bv};
#pragma unroll
        for (int c = 0; c < 6; ++c) {
            bf16x8 ah = *(const bf16x8*)&Ah[lrow * LSTR + c * 32 + lk8];
            bf16x8 al = *(const bf16x8*)&Al[lrow * LSTR + c * 32 + lk8];
            acc = __builtin_amdgcn_mfma_f32_16x16x32_bf16(ah, wh[c], acc, 0, 0, 0);
            acc = __builtin_amdgcn_mfma_f32_16x16x32_bf16(al, wh[c], acc, 0, 0, 0);
            acc = __builtin_amdgcn_mfma_f32_16x16x32_bf16(ah, wl[c], acc, 0, 0, 0);
        }
        __syncthreads();

#pragma unroll
        for (int j = 0; j < 4; ++j) {
            int row = r0 + (lane >> 4) * 4 + j;
            float v = fmaxf(acc[j], 0.0f);
            u16 hb_ = f2bf(v);
            ohi[((size_t)row << 6) + col] = hb_;
            olo[((size_t)row << 6) + col] = f2bf(v - bf2f(hb_));
        }
    }
}

__global__ __launch_bounds__(256) void dense2_mf(const u16* __restrict__ a0h,
                                                 const u16* __restrict__ a0l,
                                                 const u16* __restrict__ a1h,
                                                 const u16* __restrict__ a1l,
                                                 const u16* __restrict__ tyh,
                                                 const u16* __restrict__ tyl,
                                                 const float* __restrict__ W,
                                                 const float* __restrict__ bias,
                                                 float* __restrict__ out) {
    __shared__ u16 Ah[16 * LSTR], Al[16 * LSTR];
    __shared__ float Ls[16][48];
    const int tid = threadIdx.x, wid = tid >> 6, lane = tid & 63;
    const int lrow = lane & 15, lk8 = (lane >> 4) * 8;
    const int col = wid * 16 + lrow;
    const bool act = (wid < 3);
    const bool cok = act && (col < NCLS);

    bf16x8 wh[6], wl[6];
#pragma unroll
    for (int c = 0; c < 6; ++c) {
        bf16x8 h = 0, l = 0;
        if (cok) {
#pragma unroll
            for (int i = 0; i < 8; ++i) {
                float wv = foldW(W, c * 32 + lk8 + i, col, NCLS);
                u16 hb_ = f2bf(wv);
                h[i] = (short)hb_;
                l[i] = (short)f2bf(wv - bf2f(hb_));
            }
        }
        wh[c] = h; wl[c] = l;
    }
    float bv = cok ? bias[col] : 0.0f;
    const int srow = tid >> 4, sc4 = (tid & 15) * 4;

    for (int t = 0; t < DNT; ++t) {
        int r0 = (blockIdx.x * DNT + t) * 16;
        size_t rb = ((size_t)(r0 + srow) << 6) + sc4;
        *(ushort4*)&Ah[srow * LSTR + sc4] = *(const ushort4*)&a0h[rb];
        *(ushort4*)&Al[srow * LSTR + sc4] = *(const ushort4*)&a0l[rb];
        *(ushort4*)&Ah[srow * LSTR + 64 + sc4] = *(const ushort4*)&a1h[rb];
        *(ushort4*)&Al[srow * LSTR + 64 + sc4] = *(const ushort4*)&a1l[rb];
        *(ushort4*)&Ah[srow * LSTR + 128 + sc4] = *(const ushort4*)&tyh[rb];
        *(ushort4*)&Al[srow * LSTR + 128 + sc4] = *(const ushort4*)&tyl[rb];
        __syncthreads();

        if (act) {
            f32x4 acc = {bv, bv, bv, bv};
#pragma unroll
            for (int c = 0; c < 6; ++c) {
                bf16x8 ah = *(const bf16x8*)&Ah[lrow * LSTR + c * 32 + lk8];
                bf16x8 al = *(const bf16x8*)&Al[lrow * LSTR + c * 32 + lk8];
                acc = __builtin_amdgcn_mfma_f32_16x16x32_bf16(ah, wh[c], acc, 0, 0, 0);
                acc = __builtin_amdgcn_mfma_f32_16x16x32_bf16(al, wh[c], acc, 0, 0, 0);
                acc = __builtin_amdgcn_mfma_f32_16x16x32_bf16(ah, wl[c], acc, 0, 0, 0);
            }
#pragma unroll
            for (int j = 0; j < 4; ++j) Ls[(lane >> 4) * 4 + j][col] = acc[j];
        }
        __syncthreads();

        {   // softmax: 16 rows, one 16-lane group per row (4 rows per wave)
            int row = wid * 4 + (lane >> 4);
            int cg = lane & 15;
            float v0 = Ls[row][cg];
            float v1 = Ls[row][cg + 16];
            float v2 = (cg < 8) ? Ls[row][cg + 32] : -1e30f;
            float m = fmaxf(fmaxf(v0, v1), v2);
#pragma unroll
            for (int o = 8; o; o >>= 1) m = fmaxf(m, __shfl_xor(m, o));
            float e0 = expf(v0 - m), e1 = expf(v1 - m);
            float e2 = (cg < 8) ? expf(v2 - m) : 0.0f;
            float s = e0 + e1 + e2;
#pragma unroll
            for (int o = 8; o; o >>= 1) s += __shfl_xor(s, o);
            float inv = 1.0f / s;
            size_t ob = (size_t)(r0 + row) * NCLS;
            out[ob + cg] = e0 * inv;
            out[ob + cg + 16] = e1 * inv;
            if (cg < 8) out[ob + cg + 32] = e2 * inv;
        }
    }
}

// ---------------- host ----------------

extern "C" void kernel_launch(void* const* d_in, const int* in_sizes, int n_in,
                              void* d_out, int out_size, void* d_ws, size_t ws_size,
                              hipStream_t stream) {
    const float* x = (const float*)d_in[0];
    const int* edge_index = (const int*)d_in[1];
    const float* W1 = (const float*)d_in[2];
    const float* b1 = (const float*)d_in[3];
    const float* W2 = (const float*)d_in[4];
    const float* b2 = (const float*)d_in[5];
    float* out = (float*)d_out;

    const int* src = edge_index;
    const int* dst = edge_index + N_EDGES;

    char* ws = (char*)d_ws;
    size_t off = 0;
    auto carve = [&](size_t bytes) -> void* {
        void* p = ws + off;
        off = align256(off + bytes);
        return p;
    };
    int* gFillD = (int*)carve((size_t)NBUCK * 4);
    int* gFillS = (int*)carve((size_t)NBUCK * 4);
    size_t zero_bytes = off;
    int2* partD = (int2*)carve((size_t)NBUCK * CAPE * 8);   // 14.0 MB
    int* partS = (int*)carve((size_t)NBUCK * CAPE * 4);     // 7.0 MB
    int* csr = (int*)carve((size_t)NBUCK * CAPC * 4 + 1024);// 8.4 MB (+slack)
    int2* meta = (int2*)carve((size_t)N_NODES * 8);         // 0.8 MB
    float* dis = (float*)carve((size_t)(N_NODES + 1) * 4);  // 0.4 MB (+DUMMY)
    const size_t FB = (size_t)(N_NODES + 1) * 64 * 2;       // 12.8 MB per bf16 plane (+DUMMY row)
    u16* xb  = (u16*)carve(FB);
    u16* t1h = (u16*)carve(FB);   // Tx1 / Th1 hi
    u16* t1l = (u16*)carve(FB);   // Tx1 / Th1 lo
    u16* tyh = (u16*)carve(FB);   // L.Tx1 / L.Th1 hi
    u16* tyl = (u16*)carve(FB);   // L.Tx1 / L.Th1 lo
    u16* hh  = (u16*)carve(FB);   // h hi (gather input for layer 2)
    u16* hl  = (u16*)carve(FB);   // h lo
    // total ~120 MB

    const int WV = (N_NODES * 64) / 256;    // 25000 (one wave per node)

    hipMemsetAsync(d_ws, 0, zero_bytes, stream);
    hipMemsetAsync(dis + N_NODES, 0, 4, stream);               // dis[DUMMY] = 0
    hipMemsetAsync(xb + (size_t)N_NODES * 64, 0, 128, stream); // zero DUMMY rows of
    hipMemsetAsync(t1h + (size_t)N_NODES * 64, 0, 128, stream);//   all gather inputs
    hipMemsetAsync(hh + (size_t)N_NODES * 64, 0, 128, stream);

    pscatter_conv<<<PS_BLOCKS + CONV_BLOCKS, 256, 0, stream>>>(src, dst, gFillD, gFillS,
                                                               partD, partS, x, xb);
    build<<<2 * NBUCK, 256, 0, stream>>>(partD, partS, gFillD, gFillS, csr, meta, dis);

    // layer 1: Tx1 = L.x ; Ty = L.Tx1 ; h = relu(x@(W0-W2) + Tx1@W1 + Ty@2W2 + b1)
    spmm<<<WV, 256, 0, stream>>>(xb, dis, meta, csr, t1h, t1l);
    spmm<<<WV, 256, 0, stream>>>(t1h, dis, meta, csr, tyh, tyl);
    dense1_mf<<<DGRID, 256, 0, stream>>>(x, t1h, t1l, tyh, tyl, W1, b1, hh, hl);

    // layer 2 (t1/ty planes reused)
    spmm<<<WV, 256, 0, stream>>>(hh, dis, meta, csr, t1h, t1l);
    spmm<<<WV, 256, 0, stream>>>(t1h, dis, meta, csr, tyh, tyl);
    dense2_mf<<<DGRID, 256, 0, stream>>>(hh, hl, t1h, t1l, tyh, tyl, W2, b2, out);
}